// Round 2
// baseline (204.917 us; speedup 1.0000x reference)
//
#include <hip/hip_runtime.h>
#include <math.h>

#define BB 256
#define DD 5120
#define NN 16
#define RR 160
#define CT 192          // 160 (t) + 16 (Bm) + 16 (Cm)
#define NSPLIT 64
#define KSPLIT 80       // K per split in k1 (64 * 80 = 5120)
#define TMP_ELEMS (BB * CT)          // 49152
#define NEGA_ELEMS (DD * NN)         // 81920

// ---------------- K1: partials[s][b][c] = x[b, ks:ks+80] @ Wcat[ks:ks+80, c]
// grid: (3 c-tiles of 64, 8 b-tiles of 32, 64 k-splits) = 1536 blocks.
// Single-stage LDS (31 KB -> 5 blocks/CU), ONE barrier, no in-loop syncs.
__global__ __launch_bounds__(256) void k1_gemm(const float* __restrict__ x,
                                               const float* __restrict__ Wxdt,
                                               const float* __restrict__ Wbc,
                                               float* __restrict__ part) {
    __shared__ float xs[32][KSPLIT + 1];   // [b][k], +1 pad: in-loop reads conflict-free
    __shared__ float ws[KSPLIT][64];       // [k][c], f4-aligned rows, conflict-free
    const int tid = threadIdx.x;
    const int tx = tid & 15, ty = tid >> 4;   // tx: c-group of 4, ty: b-pair
    const int c0 = blockIdx.x * 64;
    const int b0 = blockIdx.y * 32;
    const int k0 = blockIdx.z * KSPLIT;

    // stage x tile [32 b][80 k]: 640 float4 global loads, scalar LDS writes
    for (int p = tid; p < 640; p += 256) {
        const int row = p / 20;               // 20 float4 per b-row
        const int j4  = (p % 20) * 4;
        const float4 v = *(const float4*)&x[(size_t)(b0 + row) * DD + k0 + j4];
        xs[row][j4 + 0] = v.x; xs[row][j4 + 1] = v.y;
        xs[row][j4 + 2] = v.z; xs[row][j4 + 3] = v.w;
    }
    // stage W tile [80 k][64 c]: 1280 float4 (both sources %4 aligned)
    for (int p = tid; p < 1280; p += 256) {
        const int r  = p >> 4;                // 16 float4 per k-row
        const int c4 = (p & 15) * 4;
        const int kg = k0 + r;
        const int cg = c0 + c4;
        float4 v;
        if (cg < RR) v = *(const float4*)&Wxdt[(size_t)kg * RR + cg];
        else         v = *(const float4*)&Wbc[(size_t)kg * 32 + (cg - RR)];
        *(float4*)&ws[r][c4] = v;
    }
    __syncthreads();

    float acc[2][4] = {};
    #pragma unroll 8
    for (int k = 0; k < KSPLIT; ++k) {
        const float a0 = xs[ty * 2 + 0][k];   // broadcast across tx lanes
        const float a1 = xs[ty * 2 + 1][k];
        const float4 w4 = *(const float4*)&ws[k][tx * 4];
        const float wv[4] = {w4.x, w4.y, w4.z, w4.w};
        #pragma unroll
        for (int v = 0; v < 4; ++v) {
            acc[0][v] = fmaf(a0, wv[v], acc[0][v]);
            acc[1][v] = fmaf(a1, wv[v], acc[1][v]);
        }
    }

    float* p = part + (size_t)blockIdx.z * TMP_ELEMS;
    #pragma unroll
    for (int u = 0; u < 2; ++u) {
        const int b = b0 + ty * 2 + u;
        *(float4*)&p[b * CT + c0 + tx * 4] =
            make_float4(acc[u][0], acc[u][1], acc[u][2], acc[u][3]);
    }
}

// ---------------- K_RED: tmp = sum_s partials; negA = -exp(A_log) -----------
// grid: 512 blocks x 256 = 131072 = 49152 + 81920
__global__ __launch_bounds__(256) void k_red(const float* __restrict__ part,
                                             const float* __restrict__ Alog,
                                             float* __restrict__ tmp,
                                             float* __restrict__ negA) {
    const int idx = blockIdx.x * 256 + threadIdx.x;
    if (idx < TMP_ELEMS) {
        float s = 0.f;
        #pragma unroll
        for (int z = 0; z < NSPLIT; ++z) s += part[(size_t)z * TMP_ELEMS + idx];
        tmp[idx] = s;
    } else {
        const int j = idx - TMP_ELEMS;
        negA[j] = -__expf(Alog[j]);
    }
}

// ---------------- K_DT: dt[b,d] = softplus(t @ W_dt + b_dt) -----------------
// M=256(b) x N=5120(d) x K=160. grid (80 d-tiles of 64, 8 b-tiles of 32) = 640.
// WHOLE K staged once (61.6 KB LDS -> 2 blocks/CU), ONE barrier, then a
// 160-deep uninterrupted FMA loop. micro 2b x 4d.
__global__ __launch_bounds__(256) void k_dt(const float* __restrict__ tmp,
                                            const float* __restrict__ Wdt,
                                            const float* __restrict__ bdt,
                                            float* __restrict__ dtA) {
    __shared__ float ts[32][RR + 1];   // [b][k], +1 pad
    __shared__ float ws[RR][64];       // [k][d]
    const int tid = threadIdx.x;
    const int tx = tid & 15, ty = tid >> 4;   // tx: d-group of 4, ty: b-pair
    const int d0 = blockIdx.x * 64;
    const int b0 = blockIdx.y * 32;

    // stage t tile [32 b][160 k]: 1280 float4
    for (int p = tid; p < 1280; p += 256) {
        const int row = p / 40;               // 40 float4 per b-row
        const int j4  = (p % 40) * 4;
        const float4 v = *(const float4*)&tmp[(size_t)(b0 + row) * CT + j4];
        ts[row][j4 + 0] = v.x; ts[row][j4 + 1] = v.y;
        ts[row][j4 + 2] = v.z; ts[row][j4 + 3] = v.w;
    }
    // stage W_dt tile [160 k][64 d]: 2560 float4
    for (int p = tid; p < 2560; p += 256) {
        const int r  = p >> 4;                // 16 float4 per k-row
        const int c4 = (p & 15) * 4;
        *(float4*)&ws[r][c4] = *(const float4*)&Wdt[(size_t)r * DD + d0 + c4];
    }
    __syncthreads();

    float acc[2][4] = {};
    #pragma unroll 8
    for (int k = 0; k < RR; ++k) {
        const float a0 = ts[ty * 2 + 0][k];
        const float a1 = ts[ty * 2 + 1][k];
        const float4 w4 = *(const float4*)&ws[k][tx * 4];
        const float wv[4] = {w4.x, w4.y, w4.z, w4.w};
        #pragma unroll
        for (int v = 0; v < 4; ++v) {
            acc[0][v] = fmaf(a0, wv[v], acc[0][v]);
            acc[1][v] = fmaf(a1, wv[v], acc[1][v]);
        }
    }

    const float4 bv = *(const float4*)&bdt[d0 + tx * 4];
    const float bb[4] = {bv.x, bv.y, bv.z, bv.w};
    #pragma unroll
    for (int u = 0; u < 2; ++u) {
        const int b = b0 + ty * 2 + u;
        float4 o;
        float* op = (float*)&o;
        #pragma unroll
        for (int v = 0; v < 4; ++v) {
            const float z = acc[u][v] + bb[v];
            op[v] = fmaxf(z, 0.f) + log1pf(__expf(-fabsf(z)));  // softplus
        }
        *(float4*)&dtA[(size_t)b * DD + d0 + tx * 4] = o;
    }
}

// ---------------- K_EPI: pure h0-streaming epilogue -------------------------
// y[b,d] = sum_n (exp(negA[d,n]*dt)*h0[b,d,n] + dt*x*Bm[b,n]) * Cm[b,n] + x
// grid (10 d-chunks of 512, 256 b), block 256, 2 cells/thread.
// Dominant traffic: h0 (84 MB) streamed once, fully coalesced.
__global__ __launch_bounds__(256) void k_epi(const float* __restrict__ x,
                                             const float* __restrict__ h0,
                                             const float* __restrict__ dtA,
                                             const float* __restrict__ negA,
                                             const float* __restrict__ tmp,
                                             float* __restrict__ out) {
    __shared__ float bc[32];       // Bm [0..15], Cm [16..31] for this b
    const int tid = threadIdx.x;
    const int b  = blockIdx.y;
    const int d0 = blockIdx.x * 512;
    if (tid < 32) bc[tid] = tmp[(size_t)b * CT + RR + tid];
    __syncthreads();

    #pragma unroll
    for (int r = 0; r < 2; ++r) {
        const int d = d0 + r * 256 + tid;
        const size_t cell = (size_t)b * DD + d;
        const float dt  = dtA[cell];
        const float xe  = x[cell];
        const float dtx = dt * xe;
        const float* hp = &h0[cell * NN];
        const float* ap = &negA[(size_t)d * NN];
        float acc4[4] = {xe, 0.f, 0.f, 0.f};   // split accumulators for ILP
        #pragma unroll
        for (int n4 = 0; n4 < NN; n4 += 4) {
            const float4 a4 = *(const float4*)&ap[n4];
            const float4 h4 = *(const float4*)&hp[n4];
            const float av[4] = {a4.x, a4.y, a4.z, a4.w};
            const float hv[4] = {h4.x, h4.y, h4.z, h4.w};
            #pragma unroll
            for (int q = 0; q < 4; ++q) {
                const int n = n4 + q;
                const float dA = __expf(av[q] * dt);
                const float h  = fmaf(dA, hv[q], dtx * bc[n]);
                acc4[q] = fmaf(h, bc[16 + n], acc4[q]);
            }
        }
        out[cell] = (acc4[0] + acc4[1]) + (acc4[2] + acc4[3]);
    }
}

extern "C" void kernel_launch(void* const* d_in, const int* in_sizes, int n_in,
                              void* d_out, int out_size, void* d_ws, size_t ws_size,
                              hipStream_t stream) {
    const float* x    = (const float*)d_in[0];
    const float* h0   = (const float*)d_in[1];
    const float* Wxdt = (const float*)d_in[2];
    const float* Wdt  = (const float*)d_in[3];
    const float* bdt  = (const float*)d_in[4];
    const float* Wbc  = (const float*)d_in[5];
    const float* Alog = (const float*)d_in[6];
    float* out = (float*)d_out;

    // ws layout (floats): partials[64*49152] | tmp[49152] | negA[81920]
    // dtA (256*5120 floats = 5.2 MB) ALIASES part (12.6 MB): part is dead
    // after k_red; stream ordering (k_red -> k_dt -> k_epi) makes it safe.
    float* part = (float*)d_ws;
    float* tmp  = part + (size_t)NSPLIT * TMP_ELEMS;
    float* negA = tmp + TMP_ELEMS;
    float* dtA  = part;

    k1_gemm<<<dim3(3, 8, NSPLIT), 256, 0, stream>>>(x, Wxdt, Wbc, part);
    k_red<<<dim3((TMP_ELEMS + NEGA_ELEMS) / 256), 256, 0, stream>>>(part, Alog, tmp, negA);
    k_dt<<<dim3(DD / 64, BB / 32), 256, 0, stream>>>(tmp, Wdt, bdt, dtA);
    k_epi<<<dim3(DD / 512, BB), 256, 0, stream>>>(x, h0, dtA, negA, tmp, out);
}

// Round 3
// 175.163 us; speedup vs baseline: 1.1699x; 1.1699x over previous
//
#include <hip/hip_runtime.h>
#include <math.h>

#define BB 256
#define DD 5120
#define NN 16
#define RR 160
#define CT 192          // 160 (t) + 16 (Bm) + 16 (Cm)
#define NSPLIT 32
#define TMP_ELEMS (BB * CT)          // 49152
#define NEGA_ELEMS (DD * NN)         // 81920

// ---------------- K1: partials[s][b][c] = x[b, ks:ks+160] @ Wcat[ks:ks+160, c]
// grid: (3 c-tiles, 4 b-tiles, 32 k-splits), block 256. No atomics.
// (Exact round-1 version — measured as part of the 184 us config.)
__global__ __launch_bounds__(256) void k1_gemm(const float* __restrict__ x,
                                               const float* __restrict__ Wxdt,
                                               const float* __restrict__ Wbc,
                                               float* __restrict__ part) {
    __shared__ float xs[32][68];   // [k][b] transposed (68: b128-aligned rows)
    __shared__ float ws[32][64];   // [k][c]
    const int tid = threadIdx.x;
    const int tx = tid & 15, ty = tid >> 4;
    const int c0 = blockIdx.x * 64;
    const int b0 = blockIdx.y * 64;
    const int k0 = blockIdx.z * 160;
    float acc[4][4] = {};

    for (int kc = 0; kc < 160; kc += 32) {
        // stage x tile transposed into LDS
        {
            const int i  = tid >> 3;          // 0..31
            const int j4 = (tid & 7) * 4;     // 0..28
            #pragma unroll
            for (int rep = 0; rep < 2; ++rep) {
                const int row = i + rep * 32;
                const float4 v = *(const float4*)&x[(size_t)(b0 + row) * DD + k0 + kc + j4];
                xs[j4 + 0][row] = v.x;
                xs[j4 + 1][row] = v.y;
                xs[j4 + 2][row] = v.z;
                xs[j4 + 3][row] = v.w;
            }
        }
        // stage W tile (float4 along c; both sources are %4 aligned)
        {
            const int c4 = (tid & 15) * 4;
            const int r0 = tid >> 4;          // 0..15
            #pragma unroll
            for (int rep = 0; rep < 2; ++rep) {
                const int r  = r0 + rep * 16;
                const int kg = k0 + kc + r;
                const int cg = c0 + c4;
                float4 v;
                if (cg < RR) v = *(const float4*)&Wxdt[(size_t)kg * RR + cg];
                else         v = *(const float4*)&Wbc[(size_t)kg * 32 + (cg - RR)];
                *(float4*)&ws[r][c4] = v;
            }
        }
        __syncthreads();
        #pragma unroll
        for (int k = 0; k < 32; ++k) {
            const float4 a4 = *(const float4*)&xs[k][ty * 4];
            const float4 w4 = *(const float4*)&ws[k][tx * 4];
            const float av[4] = {a4.x, a4.y, a4.z, a4.w};
            const float wv[4] = {w4.x, w4.y, w4.z, w4.w};
            #pragma unroll
            for (int u = 0; u < 4; ++u)
                #pragma unroll
                for (int v = 0; v < 4; ++v)
                    acc[u][v] = fmaf(av[u], wv[v], acc[u][v]);
        }
        __syncthreads();
    }

    float* p = part + (size_t)blockIdx.z * TMP_ELEMS;
    #pragma unroll
    for (int u = 0; u < 4; ++u) {
        const int b = b0 + ty * 4 + u;
        *(float4*)&p[b * CT + c0 + tx * 4] =
            make_float4(acc[u][0], acc[u][1], acc[u][2], acc[u][3]);
    }
}

// ---------------- K_RED: tmp = sum_s partials; negA = -exp(A_log) -----------
// grid: 512 blocks x 256 = 131072 = 49152 + 81920
__global__ __launch_bounds__(256) void k_red(const float* __restrict__ part,
                                             const float* __restrict__ Alog,
                                             float* __restrict__ tmp,
                                             float* __restrict__ negA) {
    const int idx = blockIdx.x * 256 + threadIdx.x;
    if (idx < TMP_ELEMS) {
        float s = 0.f;
        #pragma unroll
        for (int z = 0; z < NSPLIT; ++z) s += part[(size_t)z * TMP_ELEMS + idx];
        tmp[idx] = s;
    } else {
        const int j = idx - TMP_ELEMS;
        negA[j] = -__expf(Alog[j]);
    }
}

// ---------------- K_FUSED: dt dot-product + SSM epilogue, zero LDS/barriers -
// dt[b,d] = softplus(sum_k t[b,k]*Wdt[k,d] + bdt[d])
// y[b,d]  = sum_n (exp(negA[d,n]*dt)*h0[b,d,n] + dt*x*Bm[b,n]) * Cm[b,n] + x
// Thread owns one d and 4 b's. Wdt column loads are coalesced dwords;
// grid = (64 b-chunks FAST, 20 d-chunks SLOW) so 64 consecutive blocks share
// the same 164 KB Wdt panel -> L2 hits. t/Bm/Cm reads are wave-uniform ->
// scalar s_load path. Dominant traffic: h0 (84 MB) streamed once, coalesced.
__global__ __launch_bounds__(256) void k_fused(const float* __restrict__ x,
                                               const float* __restrict__ h0,
                                               const float* __restrict__ Wdt,
                                               const float* __restrict__ bdt,
                                               const float* __restrict__ tmp,
                                               const float* __restrict__ negA,
                                               float* __restrict__ out) {
    const int tid = threadIdx.x;
    const int b0 = blockIdx.x * 4;      // fast axis: b (shares Wdt panel)
    const int d0 = blockIdx.y * 256;    // slow axis: d
    const int d  = d0 + tid;
    const float* wcol = Wdt + d;

    // dt dot-product: 160-deep, no LDS, no barriers.
    float acc[4] = {0.f, 0.f, 0.f, 0.f};
    #pragma unroll 4
    for (int k4 = 0; k4 < RR; k4 += 4) {
        const float w0 = wcol[(size_t)(k4 + 0) * DD];
        const float w1 = wcol[(size_t)(k4 + 1) * DD];
        const float w2 = wcol[(size_t)(k4 + 2) * DD];
        const float w3 = wcol[(size_t)(k4 + 3) * DD];
        #pragma unroll
        for (int bi = 0; bi < 4; ++bi) {
            const float4 t4 = *(const float4*)&tmp[(size_t)(b0 + bi) * CT + k4]; // uniform -> s_load
            acc[bi] = fmaf(t4.x, w0, acc[bi]);
            acc[bi] = fmaf(t4.y, w1, acc[bi]);
            acc[bi] = fmaf(t4.z, w2, acc[bi]);
            acc[bi] = fmaf(t4.w, w3, acc[bi]);
        }
    }

    const float bdv = bdt[d];           // coalesced
    float dtv[4];
    #pragma unroll
    for (int bi = 0; bi < 4; ++bi) {
        const float z = acc[bi] + bdv;
        dtv[bi] = fmaxf(z, 0.f) + log1pf(__expf(-fabsf(z)));  // softplus
    }

    // negA[d, 0..15] once into registers (reused across the 4 b's)
    float av[16];
    {
        const float* ap = &negA[(size_t)d * NN];
        #pragma unroll
        for (int n4 = 0; n4 < NN; n4 += 4) {
            const float4 a4 = *(const float4*)&ap[n4];
            av[n4 + 0] = a4.x; av[n4 + 1] = a4.y;
            av[n4 + 2] = a4.z; av[n4 + 3] = a4.w;
        }
    }

    #pragma unroll
    for (int bi = 0; bi < 4; ++bi) {
        const size_t cell = (size_t)(b0 + bi) * DD + d;
        const float dt  = dtv[bi];
        const float xe  = x[cell];
        const float dtx = dt * xe;
        const float* hp  = &h0[cell * NN];
        const float* bmp = &tmp[(size_t)(b0 + bi) * CT + RR];  // uniform -> s_load
        float acc4[4] = {xe, 0.f, 0.f, 0.f};
        #pragma unroll
        for (int n4 = 0; n4 < NN; n4 += 4) {
            const float4 h4 = *(const float4*)&hp[n4];
            const float hv[4] = {h4.x, h4.y, h4.z, h4.w};
            #pragma unroll
            for (int q = 0; q < 4; ++q) {
                const int n = n4 + q;
                const float dA = __expf(av[n] * dt);
                const float h  = fmaf(dA, hv[q], dtx * bmp[n]);
                acc4[q] = fmaf(h, bmp[16 + n], acc4[q]);
            }
        }
        out[cell] = (acc4[0] + acc4[1]) + (acc4[2] + acc4[3]);
    }
}

extern "C" void kernel_launch(void* const* d_in, const int* in_sizes, int n_in,
                              void* d_out, int out_size, void* d_ws, size_t ws_size,
                              hipStream_t stream) {
    const float* x    = (const float*)d_in[0];
    const float* h0   = (const float*)d_in[1];
    const float* Wxdt = (const float*)d_in[2];
    const float* Wdt  = (const float*)d_in[3];
    const float* bdt  = (const float*)d_in[4];
    const float* Wbc  = (const float*)d_in[5];
    const float* Alog = (const float*)d_in[6];
    float* out = (float*)d_out;

    // ws layout (floats): partials[32*49152] | tmp[49152] | negA[81920]
    float* part = (float*)d_ws;
    float* tmp  = part + (size_t)NSPLIT * TMP_ELEMS;
    float* negA = tmp + TMP_ELEMS;

    k1_gemm<<<dim3(3, 4, NSPLIT), 256, 0, stream>>>(x, Wxdt, Wbc, part);
    k_red<<<dim3((TMP_ELEMS + NEGA_ELEMS) / 256), 256, 0, stream>>>(part, Alog, tmp, negA);
    k_fused<<<dim3(BB / 4, DD / 256), 256, 0, stream>>>(x, h0, Wdt, bdt, tmp, negA, out);
}